// Round 13
// baseline (112.456 us; speedup 1.0000x reference)
//
#include <hip/hip_runtime.h>

#define DZ 512
#define DT 66048
#define NTILE 2064  // 32-col tiles
#define SV_JITTER 1e-4f

typedef __attribute__((ext_vector_type(8))) short bf8;
typedef __attribute__((ext_vector_type(4))) float f4;

__device__ __forceinline__ short f2bf(float f) {
  unsigned u = __builtin_bit_cast(unsigned, f);
  return (short)((u + 0x7FFFu + ((u >> 16) & 1u)) >> 16);
}

__device__ __forceinline__ bf8 cvt8(float4 a, float4 b) {
  bf8 r = { f2bf(a.x), f2bf(a.y), f2bf(a.z), f2bf(a.w),
            f2bf(b.x), f2bf(b.y), f2bf(b.z), f2bf(b.w) };
  return r;
}

// tril/jitter cvt: element t has k-index kbase+t
__device__ __forceinline__ bf8 cvt8_tril(float4 x, float4 y, int kbase, int diag) {
  float v[8] = {x.x, x.y, x.z, x.w, y.x, y.y, y.z, y.w};
  bf8 r;
  #pragma unroll
  for (int t = 0; t < 8; ++t) {
    int k = kbase + t;
    float val = (k < diag) ? v[t] : ((k == diag) ? v[t] + SV_JITTER : 0.f);
    r[t] = f2bf(val);
  }
  return r;
}

// 256 blocks (1/CU) x 512 threads (8 waves). Per round the block's 32-col
// panel (contiguous 64KB of Lyz/Lz) is staged global->REG->frag-layout-LDS:
// each load instruction reads 8 rows x 128B (8 FULL cache lines; consecutive
// i advance 8 parallel sequential streams). ds_write is bank-minimal
// (8 distinct quads via row_off). A (eps_z) in registers af[16], loaded once.
// Compute: linear lane*16B ds_read_b128 + cvt + 2 MFMA per K-step, no global.
// Stage loads issue at round start (oldest); diag next; compute hides both;
// ds_write + one barrier per round. acc: col=lane&15, row=4*(lane>>4)+reg.
__global__ __launch_bounds__(512, 2)
void sv_kernel(const float* __restrict__ mv, const float* __restrict__ Lz,
               const float* __restrict__ Ly, const float* __restrict__ Lyz,
               const float* __restrict__ eps, float* __restrict__ out) {
  // frag layout (floats): g*8192 + kk*512 + h*256 + 4*lane holds
  //   L[col0+16g+(lane&15)][32kk + 8*(lane>>4) + 4h .. +3]
  __shared__ float Bp[2][16384];  // 2 x 64 KB

  const int tid = threadIdx.x;
  const int lane = tid & 63;
  const int wv = tid >> 6;  // 0..7 = sample group
  const int lcol = lane & 15;
  const int q = lane >> 4;
  const int b = blockIdx.x;

  // ---- staging geometry: wave wv owns rows (wv&3)*8..+7, column-half wv>>2.
  // Instr i, lane l: row_off=l>>3, cc=l&7; src row=(wv&3)*8+row_off,
  // float4-col c4 = (wv>>2)*64 + i*8 + cc  (8 rows x 128B full lines).
  // Dest float D(i) = g*8192 + (half*8+i)*512 + h*256 + 64q' + 4*lcol'
  //   with g=(wv&3)>>1, lcol'=((wv&3)&1)*8+row_off, q'=cc>>1, h=cc&1.
  const int w3 = wv & 3, half = wv >> 2;
  const int row_off = lane >> 3, cc = lane & 7;
  const int srow = w3 * 8 + row_off;
  const int sbase = srow * 512 + half * 256 + cc * 4;  // + i*32 per instr
  const int dbase = (w3 >> 1) * 8192 + half * 4096 + (cc & 1) * 256 +
                    (cc >> 1) * 64 + 4 * (((w3 & 1) * 8) + row_off);  // + i*512

  float4 sv[8];  // staged panel floats (32 VGPR), static indices only
  auto stage_load = [&](int T) {
    const float* Ls = (T < 16) ? (Lz + (size_t)(32 * T) * DZ)
                               : (Lyz + (size_t)(32 * T - DZ) * DZ);
    #pragma unroll
    for (int i = 0; i < 8; ++i) sv[i] = *(const float4*)(Ls + sbase + i * 32);
  };
  auto stage_write = [&](float* buf) {
    #pragma unroll
    for (int i = 0; i < 8; ++i) *(float4*)(buf + dbase + i * 512) = sv[i];
  };

  // ---- prologue: stage tile(b) + fill af[16] (static unroll), write, barrier
  stage_load(b);
  bf8 af[16];
  {
    const float* ar = eps + (size_t)(16 * wv + lcol) * DT + 8 * q;
    #pragma unroll
    for (int kk = 0; kk < 16; ++kk) {
      const float4 x = *(const float4*)(ar + 32 * kk);
      const float4 y = *(const float4*)(ar + 32 * kk + 4);
      af[kk] = cvt8(x, y);
    }
  }
  stage_write(&Bp[0][0]);
  __syncthreads();

  #pragma unroll 1
  for (int r = 0; r < 9; ++r) {
    const int T = r * 256 + b;
    if (T >= NTILE) break;
    const bool isz = (T < 16);
    const int Tn = T + 256;
    const bool have_next = (Tn < NTILE);

    if (have_next) stage_load(Tn);  // oldest vmem of the round (sequential)

    // diag-step loads (y tiles): land under compute
    float4 dax, day, db0x, db0y, db1x, db1y;
    if (!isz) {
      const int nb = T - 16;  // 32x32 Ly block
      const float* pa =
          eps + (size_t)(16 * wv + lcol) * DT + DZ + (size_t)nb * 32 + 8 * q;
      dax = *(const float4*)pa; day = *(const float4*)(pa + 4);
      const float* pb0 = Ly + ((size_t)nb * 32 + lcol) * 32 + 8 * q;
      db0x = *(const float4*)pb0; db0y = *(const float4*)(pb0 + 4);
      const float* pb1 = Ly + ((size_t)nb * 32 + 16 + lcol) * 32 + 8 * q;
      db1x = *(const float4*)pb1; db1y = *(const float4*)(pb1 + 4);
    }

    // ---- compute from Bp[r&1]: LDS + VALU + MFMA only
    const float* pan = &Bp[r & 1][0];
    f4 acc0 = f4{0.f, 0.f, 0.f, 0.f};
    f4 acc1 = f4{0.f, 0.f, 0.f, 0.f};
    const int c0 = 32 * T + lcol;
    if (isz) {
      #pragma unroll
      for (int kk = 0; kk < 16; ++kk) {
        const float4 x0 = *(const float4*)(pan + kk * 512 + 4 * lane);
        const float4 y0 = *(const float4*)(pan + kk * 512 + 256 + 4 * lane);
        const float4 x1 = *(const float4*)(pan + 8192 + kk * 512 + 4 * lane);
        const float4 y1 = *(const float4*)(pan + 8192 + kk * 512 + 256 + 4 * lane);
        const bf8 b0 = cvt8_tril(x0, y0, 32 * kk + 8 * q, c0);
        const bf8 b1 = cvt8_tril(x1, y1, 32 * kk + 8 * q, c0 + 16);
        acc0 = __builtin_amdgcn_mfma_f32_16x16x32_bf16(af[kk], b0, acc0, 0, 0, 0);
        acc1 = __builtin_amdgcn_mfma_f32_16x16x32_bf16(af[kk], b1, acc1, 0, 0, 0);
      }
    } else {
      #pragma unroll
      for (int kk = 0; kk < 16; ++kk) {
        const float4 x0 = *(const float4*)(pan + kk * 512 + 4 * lane);
        const float4 y0 = *(const float4*)(pan + kk * 512 + 256 + 4 * lane);
        const float4 x1 = *(const float4*)(pan + 8192 + kk * 512 + 4 * lane);
        const float4 y1 = *(const float4*)(pan + 8192 + kk * 512 + 256 + 4 * lane);
        const bf8 b0 = cvt8(x0, y0);
        const bf8 b1 = cvt8(x1, y1);
        acc0 = __builtin_amdgcn_mfma_f32_16x16x32_bf16(af[kk], b0, acc0, 0, 0, 0);
        acc1 = __builtin_amdgcn_mfma_f32_16x16x32_bf16(af[kk], b1, acc1, 0, 0, 0);
      }
      // block-diag einsum step
      const bf8 afd = cvt8(dax, day);
      const bf8 dbf0 = cvt8_tril(db0x, db0y, 8 * q, lcol);
      const bf8 dbf1 = cvt8_tril(db1x, db1y, 8 * q, 16 + lcol);
      acc0 = __builtin_amdgcn_mfma_f32_16x16x32_bf16(afd, dbf0, acc0, 0, 0, 0);
      acc1 = __builtin_amdgcn_mfma_f32_16x16x32_bf16(afd, dbf1, acc1, 0, 0, 0);
    }

    // ---- epilogue: both 64B halves of each 128B out line, back-to-back
    {
      const float m0 = mv[c0], m1 = mv[c0 + 16];
      #pragma unroll
      for (int rr = 0; rr < 4; ++rr) {
        const size_t rowoff = (size_t)(16 * wv + 4 * q + rr) * DT;
        out[rowoff + c0] = acc0[rr] + m0;
        out[rowoff + c0 + 16] = acc1[rr] + m1;
      }
    }

    // ---- write-late: staged regs -> other buffer, then round barrier
    if (have_next) stage_write(&Bp[(r + 1) & 1][0]);
    __syncthreads();
  }
}

extern "C" void kernel_launch(void* const* d_in, const int* in_sizes, int n_in,
                              void* d_out, int out_size, void* d_ws, size_t ws_size,
                              hipStream_t stream) {
  const float* m   = (const float*)d_in[0];
  const float* Lz  = (const float*)d_in[1];
  const float* Ly  = (const float*)d_in[2];
  const float* Lyz = (const float*)d_in[3];
  const float* eps = (const float*)d_in[4];
  float* out = (float*)d_out;
  sv_kernel<<<dim3(256), dim3(512), 0, stream>>>(m, Lz, Ly, Lyz, eps, out);
}

// Round 14
// 50.834 us; speedup vs baseline: 2.2122x; 2.2122x over previous
//
#include <hip/hip_runtime.h>

#define DZ 512
#define DT 66048
#define NTILE 2064  // 32-col tiles
#define SV_JITTER 1e-4f

typedef __attribute__((ext_vector_type(8))) short bf8;
typedef __attribute__((ext_vector_type(4))) short bf4;
typedef __attribute__((ext_vector_type(4))) float f4;

__device__ __forceinline__ short f2bf(float f) {
  unsigned u = __builtin_bit_cast(unsigned, f);
  return (short)((u + 0x7FFFu + ((u >> 16) & 1u)) >> 16);
}

__device__ __forceinline__ bf8 cvt8(float4 a, float4 b) {
  bf8 r = { f2bf(a.x), f2bf(a.y), f2bf(a.z), f2bf(a.w),
            f2bf(b.x), f2bf(b.y), f2bf(b.z), f2bf(b.w) };
  return r;
}

// tril/jitter cvt: element t has k-index kbase+t
__device__ __forceinline__ bf8 cvt8_tril(float4 x, float4 y, int kbase, int diag) {
  float v[8] = {x.x, x.y, x.z, x.w, y.x, y.y, y.z, y.w};
  bf8 r;
  #pragma unroll
  for (int t = 0; t < 8; ++t) {
    int k = kbase + t;
    float val = (k < diag) ? v[t] : ((k == diag) ? v[t] + SV_JITTER : 0.f);
    r[t] = f2bf(val);
  }
  return r;
}

// 256 blocks (1/CU) x 512 threads (8 waves). LDS = 160KB exactly:
//   Afrag 128KB: eps_z bf16, frag layout (region kk*8+mi, slot=lane), staged ONCE.
//   Bpan   32KB: current tile's B panel, row-major [32][512] bf16, 1KB/row,
//                16B-slot XOR swizzle (slot^=row&7), tril/jitter baked in.
// Per round the panel source (contiguous 64KB of Lyz/Lz) is read as 8 instrs
// of f=i*512+tid -> every wave-instruction is a contiguous 1KB burst (true
// sequential DRAM streams). Staged floats: 32 VGPR, load-early/write-late.
// K-loop: pure ds_read_b128 + MFMA (both operands pre-converted bf16).
// acc layout per mfma_f32_16x16x32_bf16: col=lane&15, row=4*(lane>>4)+reg.
__global__ __launch_bounds__(512, 2)
void sv_kernel(const float* __restrict__ mv, const float* __restrict__ Lz,
               const float* __restrict__ Ly, const float* __restrict__ Lyz,
               const float* __restrict__ eps, float* __restrict__ out) {
  __shared__ short Afrag[128 * 512];  // 128 KB
  __shared__ short Bpan[32 * 512];    //  32 KB

  const int tid = threadIdx.x;
  const int lane = tid & 63;
  const int wv = tid >> 6;  // 0..7 = sample group (rows 16wv..+15)
  const int lcol = lane & 15;
  const int q = lane >> 4;
  const int b = blockIdx.x;

  float4 sv[8];  // staged panel floats (32 VGPR), static indices only
  auto stage_load = [&](int T) {
    const float* Ls = (T < 16) ? (Lz + (size_t)(32 * T) * DZ)
                               : (Lyz + (size_t)(32 * T - DZ) * DZ);
    #pragma unroll
    for (int i = 0; i < 8; ++i)
      sv[i] = *(const float4*)(Ls + (size_t)4 * (i * 512 + tid));
  };
  // float4 f covers panel row ro=f>>7, k=4*(f&127)..+3 -> 8B bf16 at
  // ro*1024 + ((slot16 ^ (ro&7))<<4) + (c4&1)*8, slot16=c4>>1.
  auto stage_write = [&](int T) {
    #pragma unroll
    for (int i = 0; i < 8; ++i) {
      const int f = i * 512 + tid;
      const int ro = f >> 7;
      const int c4 = f & 127;
      const float v[4] = {sv[i].x, sv[i].y, sv[i].z, sv[i].w};
      bf4 w;
      if (T < 16) {  // z tile: tril + jitter baked in at stage time
        const int gcol = 32 * T + ro;
        #pragma unroll
        for (int t = 0; t < 4; ++t) {
          const int k = 4 * c4 + t;
          const float val =
              (k < gcol) ? v[t] : ((k == gcol) ? v[t] + SV_JITTER : 0.f);
          w[t] = f2bf(val);
        }
      } else {
        #pragma unroll
        for (int t = 0; t < 4; ++t) w[t] = f2bf(v[t]);
      }
      const int off = (ro << 10) + ((((c4 >> 1) ^ (ro & 7))) << 4) + ((c4 & 1) << 3);
      *(bf4*)((char*)Bpan + off) = w;
    }
  };
  // B-frag read: row R=16g+lcol, k0=32kk+8q -> swizzled 16B slot 4kk+q
  auto readB = [&](int g, int kk) -> bf8 {
    const int R = 16 * g + lcol;
    const int off = (R << 10) + (((4 * kk + q) ^ (R & 7)) << 4);
    return *(const bf8*)((const char*)Bpan + off);
  };

  // ---- prologue: issue tile(b) panel stream (oldest), stage Afrag once
  stage_load(b);
  {  // eps_z -> Afrag (R4-proven): region r = kk*8+mi, slot=lane
    const int slot = lane;
    const int r0 = wv * 16;
    #pragma unroll 4
    for (int i = 0; i < 16; ++i) {
      const int r = r0 + i;  // mi=r&7, kk=r>>3
      const float* p = eps + (size_t)(16 * (r & 7) + (slot & 15)) * DT +
                       (r >> 3) * 32 + (slot >> 4) * 8;
      const float4 x = *(const float4*)p;
      const float4 y = *(const float4*)(p + 4);
      *(bf8*)&Afrag[r * 512 + slot * 8] = cvt8(x, y);
    }
  }
  stage_write(b);
  __syncthreads();

  #pragma unroll 1
  for (int r = 0; r < 9; ++r) {
    const int T = r * 256 + b;
    if (T >= NTILE) break;
    const bool isz = (T < 16);
    const int Tn = T + 256;
    const bool have_next = (Tn < NTILE);

    if (have_next) stage_load(Tn);  // sequential burst, oldest vmem of round

    // diag-step loads (y tiles): land under compute
    float4 dax, day, db0x, db0y, db1x, db1y;
    if (!isz) {
      const int nb = T - 16;  // 32x32 Ly block
      const float* pa =
          eps + (size_t)(16 * wv + lcol) * DT + DZ + (size_t)nb * 32 + 8 * q;
      dax = *(const float4*)pa; day = *(const float4*)(pa + 4);
      const float* pb0 = Ly + ((size_t)nb * 32 + lcol) * 32 + 8 * q;
      db0x = *(const float4*)pb0; db0y = *(const float4*)(pb0 + 4);
      const float* pb1 = Ly + ((size_t)nb * 32 + 16 + lcol) * 32 + 8 * q;
      db1x = *(const float4*)pb1; db1y = *(const float4*)(pb1 + 4);
    }

    // ---- compute: pure LDS + MFMA (both operands pre-converted bf16)
    f4 acc0 = f4{0.f, 0.f, 0.f, 0.f};
    f4 acc1 = f4{0.f, 0.f, 0.f, 0.f};
    #pragma unroll
    for (int kk = 0; kk < 16; ++kk) {
      const bf8 af = *(const bf8*)&Afrag[(kk * 8 + wv) * 512 + lane * 8];
      const bf8 b0 = readB(0, kk);
      const bf8 b1 = readB(1, kk);
      acc0 = __builtin_amdgcn_mfma_f32_16x16x32_bf16(af, b0, acc0, 0, 0, 0);
      acc1 = __builtin_amdgcn_mfma_f32_16x16x32_bf16(af, b1, acc1, 0, 0, 0);
    }
    if (!isz) {  // block-diag einsum step
      const bf8 afd = cvt8(dax, day);
      const bf8 dbf0 = cvt8_tril(db0x, db0y, 8 * q, lcol);
      const bf8 dbf1 = cvt8_tril(db1x, db1y, 8 * q, 16 + lcol);
      acc0 = __builtin_amdgcn_mfma_f32_16x16x32_bf16(afd, dbf0, acc0, 0, 0, 0);
      acc1 = __builtin_amdgcn_mfma_f32_16x16x32_bf16(afd, dbf1, acc1, 0, 0, 0);
    }

    // ---- epilogue: both 64B halves of each 128B out line, back-to-back
    {
      const int c0 = 32 * T + lcol;
      const float m0 = mv[c0], m1 = mv[c0 + 16];
      #pragma unroll
      for (int rr = 0; rr < 4; ++rr) {
        const size_t rowoff = (size_t)(16 * wv + 4 * q + rr) * DT;
        out[rowoff + c0] = acc0[rr] + m0;
        out[rowoff + c0 + 16] = acc1[rr] + m1;
      }
    }

    __syncthreads();                 // all waves done reading Bpan
    if (have_next) stage_write(Tn);  // write-late (waits only sv loads)
    __syncthreads();                 // new panel visible
  }
}

extern "C" void kernel_launch(void* const* d_in, const int* in_sizes, int n_in,
                              void* d_out, int out_size, void* d_ws, size_t ws_size,
                              hipStream_t stream) {
  const float* m   = (const float*)d_in[0];
  const float* Lz  = (const float*)d_in[1];
  const float* Ly  = (const float*)d_in[2];
  const float* Lyz = (const float*)d_in[3];
  const float* eps = (const float*)d_in[4];
  float* out = (float*)d_out;
  sv_kernel<<<dim3(256), dim3(512), 0, stream>>>(m, Lz, Ly, Lyz, eps, out);
}